// Round 7
// baseline (184.397 us; speedup 1.0000x reference)
//
#include <hip/hip_runtime.h>
#include <stdint.h>
#include <stddef.h>

#define N_NODES 100000
#define N_EDGES 1600000
#define F_IN 128
#define EMB 128
#define HEADS 4
#define D_HEAD 32
#define HIDDEN 256
#define BATCH 2048
#define CANDS 16
#define NSLOTS 32768  /* BATCH*CANDS slots, one per index (dups share canonical srclist) */
#define WTROWS 144    /* 128 W cols + 8 att-projection rows + 8 zero pad */
#define STR 136       /* padded row stride (shorts) */

/* persistent mega-kernel: 1024 blocks (4/CU capacity) self-schedule work units
   via a global ticket. Units: wx [0,782) -> scatter [782,2345) -> msg [2345,2601).
   wx-first = LPT; contiguous wx lets a block keep wt staged across units. */
#define WX_UNITS 782     /* ceil(N_NODES/128); 2 chunks of 64 rows per unit */
#define SCAT_UNITS 1563  /* ceil(400000/256); 1024 edges per unit */
#define MSG_UNITS 256    /* 8 batch rows per unit */
#define N_UNITS (WX_UNITS + SCAT_UNITS + MSG_UNITS)
#define EDGE_QUADS 400000
#define PERSIST_BLOCKS 1024

typedef __attribute__((ext_vector_type(8))) short v8s;
typedef __attribute__((ext_vector_type(4))) float v4f;

__device__ __forceinline__ unsigned short f2bs(float f) {
  unsigned int u = __builtin_bit_cast(unsigned int, f);
  u = (u + 0x7fffu + ((u >> 16) & 1u)) >> 16;
  return (unsigned short)u;
}
__device__ __forceinline__ float bs2f(unsigned int s) {
  unsigned int u = (s & 0xffffu) << 16;
  return __builtin_bit_cast(float, u);
}

// ------- prep: padded Wt^T (+att-projection rows) + slot-map dedup (no memset) -
// nidx[v] = some slot i with idx[i]==v (last writer wins). Poison-proof:
// consumers validate idx[nidx[dst]]==dst. Also zeroes cnt + the mega ticket.
__global__ __launch_bounds__(256) void k_prep(const float* __restrict__ W,
                                              const float* __restrict__ att_src,
                                              const float* __restrict__ att_dst,
                                              unsigned short* __restrict__ Wtp,
                                              const int* __restrict__ idx,
                                              int* __restrict__ nidx,
                                              int* __restrict__ cnt,
                                              int* __restrict__ ticket) {
  int i = blockIdx.x * 256 + threadIdx.x;
  if (i == 0) *ticket = 0;
  if (i < 128 * STR) {
    int r = i / STR, c = i - r * STR;
    Wtp[i] = (c < 128) ? f2bs(W[c * 128 + r]) : (unsigned short)0;
  } else if (i < WTROWS * STR) {
    int ii = i - 128 * STR;
    int r = ii / STR, c = ii - r * STR;  // r: 0..15
    unsigned short v = 0;
    if (c < 128 && r < 8) {
      const float* att = (r < 4) ? att_src : att_dst;
      int hh = r & 3;
      float s = 0.f;
#pragma unroll
      for (int d = 0; d < 32; ++d) s += W[c * 128 + hh * 32 + d] * att[hh * 32 + d];
      v = f2bs(s);
    }
    Wtp[i] = v;
  }
  if (i < NSLOTS) {
    cnt[i] = 0;           // zero-init scatter counters in-kernel (no memset)
    nidx[idx[i]] = i;     // plain store; any winner is canonical
  }
}

// ---- MEGA (persistent): wx (MFMA) + scatter + msg, ticket self-scheduling ----
__global__ __launch_bounds__(256) void k_mega(const float* __restrict__ x,
                                              const unsigned short* __restrict__ Wtp,
                                              unsigned short* __restrict__ Wx,
                                              float* __restrict__ a_s,
                                              float* __restrict__ a_d,
                                              const int* __restrict__ ei,
                                              const int* __restrict__ idx,
                                              const int* __restrict__ nidx,
                                              int* __restrict__ cnt,
                                              int* __restrict__ srclist,
                                              const float* __restrict__ message,
                                              const float* __restrict__ fc_w,
                                              const float* __restrict__ fc_b,
                                              float* __restrict__ msg,
                                              int* __restrict__ ticket) {
  __shared__ unsigned short smem[WTROWS * STR];  // 39168 B, role-unioned
  __shared__ int sU;
  int tid = threadIdx.x;
  bool wtValid = false;

  for (;;) {
    if (tid == 0) sU = atomicAdd(ticket, 1);
    __syncthreads();
    int u = sU;
    __syncthreads();  // protect sU before next write; all threads hold u in reg
    if (u >= N_UNITS) return;

    if (u < WX_UNITS) {
      // ================= wx: Wx = x @ W, permuted-native output ==============
      // Wx[row*128 + m*8 + nt] = C[row, nt*16+m]; consumer maps head = k>>1.
      unsigned short* wt = smem;
      if (!wtValid) {
        const uint4* s = (const uint4*)Wtp;
        uint4* d = (uint4*)wt;
#pragma unroll
        for (int it = 0; it < 10; ++it) {
          int i = it * 256 + tid;
          if (i < WTROWS * STR / 8) d[i] = s[i];
        }
        __syncthreads();
        wtValid = true;
      }

      int w = tid >> 6, lane = tid & 63;
      int m = lane & 15, quad = lane >> 4;

      for (int chunk = 0; chunk < 2; ++chunk) {
        int rbase = u * 128 + chunk * 64;
        int gr = rbase + w * 16 + m;
        if (gr >= N_NODES) gr = N_NODES - 1;
        const float* xrow = x + (size_t)gr * 128;

        v8s afrag[4];
#pragma unroll
        for (int t = 0; t < 4; ++t) {
          const float4* gp = (const float4*)(xrow + t * 32 + quad * 8);
          float4 f0 = gp[0], f1 = gp[1];
          v8s a;
          a[0] = (short)f2bs(f0.x); a[1] = (short)f2bs(f0.y);
          a[2] = (short)f2bs(f0.z); a[3] = (short)f2bs(f0.w);
          a[4] = (short)f2bs(f1.x); a[5] = (short)f2bs(f1.y);
          a[6] = (short)f2bs(f1.z); a[7] = (short)f2bs(f1.w);
          afrag[t] = a;
        }

        v4f acc[9];
#pragma unroll
        for (int nt = 0; nt < 9; ++nt) {
          v4f a0 = {0.f, 0.f, 0.f, 0.f};
          const unsigned short* brow = wt + (size_t)(nt * 16 + m) * STR;
#pragma unroll
          for (int t = 0; t < 4; ++t) {
            v8s b = *(const v8s*)(brow + t * 32 + quad * 8);
            a0 = __builtin_amdgcn_mfma_f32_16x16x32_bf16(afrag[t], b, a0, 0, 0, 0);
          }
          acc[nt] = a0;
        }

#pragma unroll
        for (int r = 0; r < 4; ++r) {
          int orow = rbase + w * 16 + quad * 4 + r;
          if (orow < N_NODES) {
            if (m < 4) a_s[(size_t)orow * 4 + m] = acc[8][r];
            else if (m < 8) a_d[(size_t)orow * 4 + m - 4] = acc[8][r];
            v8s v;
#pragma unroll
            for (int nt = 0; nt < 8; ++nt) v[nt] = (short)f2bs(acc[nt][r]);
            *(v8s*)(&Wx[(size_t)orow * 128 + m * 8]) = v;
          }
        }
      }
    } else if (u < WX_UNITS + SCAT_UNITS) {
      // ============ scatter: 4 edges/thread, batched-ILP chains ==============
      int e4 = (u - WX_UNITS) * 256 + tid;
      if (e4 < EDGE_QUADS) {
        int base = e4 * 4;
        int4 d4 = *(const int4*)(ei + N_EDGES + base);  // dsts
        int4 s4 = *(const int4*)(ei + base);            // srcs
        int dst[4] = {d4.x, d4.y, d4.z, d4.w};
        int src[4] = {s4.x, s4.y, s4.z, s4.w};
        unsigned int ni[4];
#pragma unroll
        for (int j = 0; j < 4; ++j) ni[j] = (unsigned int)nidx[dst[j]];
        bool ok[4];
#pragma unroll
        for (int j = 0; j < 4; ++j) {
          unsigned int c = ni[j] < NSLOTS ? ni[j] : 0u;
          ok[j] = (ni[j] < NSLOTS) && (idx[c] == dst[j]);
        }
#pragma unroll
        for (int j = 0; j < 4; ++j) {
          if (ok[j]) {
            int pos = atomicAdd(&cnt[ni[j]], 1);
            if (pos < 64) srclist[ni[j] * 64 + pos] = src[j];
          }
        }
      }
    } else {
      // ================= msg: msg = message @ fc_w.T + fc_b ==================
      wtValid = false;  // role overwrites smem
      float* Sm = (float*)smem;            // [8][256] = 8 KB
      float* red = ((float*)smem) + 2048;  // [8*128]  = 4 KB
      int b0 = (u - WX_UNITS - SCAT_UNITS) * 8;
      for (int i = tid; i < 8 * 256; i += 256)
        Sm[i] = message[(size_t)b0 * 256 + i];
      __syncthreads();
      int e = tid & 127, half = tid >> 7;
      float acc[8];
#pragma unroll
      for (int r = 0; r < 8; ++r) acc[r] = 0.f;
      const float* wrow = fc_w + (size_t)e * 256 + half * 128;
      for (int k = 0; k < 128; k += 4) {
        float4 w4 = *(const float4*)(wrow + k);
#pragma unroll
        for (int r = 0; r < 8; ++r) {
          float4 m4 = *(const float4*)(&Sm[r * 256 + half * 128 + k]);
          acc[r] += m4.x * w4.x + m4.y * w4.y + m4.z * w4.z + m4.w * w4.w;
        }
      }
      __syncthreads();
      if (half == 0) {
#pragma unroll
        for (int r = 0; r < 8; ++r) red[r * 128 + e] = acc[r];
      }
      __syncthreads();
      if (half == 1) {
#pragma unroll
        for (int r = 0; r < 8; ++r) red[r * 128 + e] += acc[r];
      }
      __syncthreads();
      for (int i = tid; i < 1024; i += 256)
        msg[(size_t)b0 * 128 + i] = red[i] + fc_b[i & 127];
      __syncthreads();  // smem reuse safety before next unit
    }
  }
}

// ---- per-slot aggregation + fused scoring: block b = 16 cands of batch row b --
// Wx is column-permuted (see wx role); lane li's k-th value is true col k*16+li,
// head = k>>1. All attention weights kept per-head (float4), selected by k>>1.
__global__ __launch_bounds__(256) void k_aggscore(const float* __restrict__ a_s,
                                                  const float* __restrict__ a_d,
                                                  const unsigned short* __restrict__ Wx,
                                                  const int* __restrict__ idx,
                                                  const int* __restrict__ nidx,
                                                  const int* __restrict__ cnt,
                                                  const int* __restrict__ srclist,
                                                  const int* __restrict__ ei,
                                                  const float* __restrict__ bias,
                                                  const float* __restrict__ msg,
                                                  float* __restrict__ out) {
  __shared__ int sS[16][64];
  __shared__ float sW[16][64 * 4];
  __shared__ float sdots[16];
  int w = threadIdx.x >> 6, lane = threadIdx.x & 63;
  int q = lane >> 4, li = lane & 15;
  int wq = w * 4 + q;
  int b = blockIdx.x;            // batch row
  int wid = b * 16 + wq;         // slot = (batch b, cand wq)
  int dst = idx[wid];
  int ci = nidx[dst];            // canonical slot owning srclist/cnt for dst
  int degRaw = cnt[ci];
  int deg = degRaw < 64 ? degRaw : 64;
  float4 ad4 = *(const float4*)(a_d + (size_t)dst * 4);
  float4 dsum = {0.f, 0.f, 0.f, 0.f};
  for (int t = li; t < deg; t += 16) {
    int sv = srclist[ci * 64 + t];
    float4 as = *(const float4*)(a_s + (size_t)sv * 4);
    float e0 = as.x + ad4.x; e0 = e0 > 0.f ? e0 : 0.2f * e0;
    float e1 = as.y + ad4.y; e1 = e1 > 0.f ? e1 : 0.2f * e1;
    float e2 = as.z + ad4.z; e2 = e2 > 0.f ? e2 : 0.2f * e2;
    float e3 = as.w + ad4.w; e3 = e3 > 0.f ? e3 : 0.2f * e3;
    float4 w4;
    w4.x = __expf(e0); w4.y = __expf(e1);
    w4.z = __expf(e2); w4.w = __expf(e3);
    sS[wq][t] = sv;
    *(float4*)(&sW[wq][t * 4]) = w4;
    dsum.x += w4.x; dsum.y += w4.y; dsum.z += w4.z; dsum.w += w4.w;
  }
  // sS/sW are quarter-wave-private: same-wave LDS ordering suffices
  asm volatile("s_waitcnt lgkmcnt(0)" ::: "memory");

#pragma unroll
  for (int o = 8; o >= 1; o >>= 1) {
    dsum.x += __shfl_xor(dsum.x, o);
    dsum.y += __shfl_xor(dsum.y, o);
    dsum.z += __shfl_xor(dsum.z, o);
    dsum.w += __shfl_xor(dsum.w, o);
  }

  // self-loop weights, ALL four heads (lane's 8 elems span heads k>>1=0..3)
  float4 as4 = *(const float4*)(a_s + (size_t)dst * 4);
  float s0 = as4.x + ad4.x; s0 = s0 > 0.f ? s0 : 0.2f * s0;
  float s1 = as4.y + ad4.y; s1 = s1 > 0.f ? s1 : 0.2f * s1;
  float s2 = as4.z + ad4.z; s2 = s2 > 0.f ? s2 : 0.2f * s2;
  float s3 = as4.w + ad4.w; s3 = s3 > 0.f ? s3 : 0.2f * s3;
  float wself[4];
  wself[0] = __expf(s0); wself[1] = __expf(s1);
  wself[2] = __expf(s2); wself[3] = __expf(s3);
  float den4[4];
  den4[0] = dsum.x + wself[0]; den4[1] = dsum.y + wself[1];
  den4[2] = dsum.z + wself[2]; den4[3] = dsum.w + wself[3];

  float acc[8];
  {
    uint4 u = *(const uint4*)(Wx + (size_t)dst * 128 + li * 8);
    acc[0] = wself[0] * bs2f(u.x); acc[1] = wself[0] * bs2f(u.x >> 16);
    acc[2] = wself[1] * bs2f(u.y); acc[3] = wself[1] * bs2f(u.y >> 16);
    acc[4] = wself[2] * bs2f(u.z); acc[5] = wself[2] * bs2f(u.z >> 16);
    acc[6] = wself[3] * bs2f(u.w); acc[7] = wself[3] * bs2f(u.w >> 16);
  }

  if (degRaw > 64) {
    // correctness-only fallback (P ~ 1e-20): serial full-edge rescan
    den4[0] = wself[0]; den4[1] = wself[1];
    den4[2] = wself[2]; den4[3] = wself[3];
    for (int e = 0; e < N_EDGES; ++e) {
      if (ei[N_EDGES + e] == dst) {
        int sv = ei[e];
        float4 as = *(const float4*)(a_s + (size_t)sv * 4);
        float e0 = as.x + ad4.x; e0 = e0 > 0.f ? e0 : 0.2f * e0;
        float e1 = as.y + ad4.y; e1 = e1 > 0.f ? e1 : 0.2f * e1;
        float e2 = as.z + ad4.z; e2 = e2 > 0.f ? e2 : 0.2f * e2;
        float e3 = as.w + ad4.w; e3 = e3 > 0.f ? e3 : 0.2f * e3;
        float wa0 = __expf(e0), wa1 = __expf(e1);
        float wa2 = __expf(e2), wa3 = __expf(e3);
        den4[0] += wa0; den4[1] += wa1; den4[2] += wa2; den4[3] += wa3;
        uint4 u = *(const uint4*)(Wx + (size_t)sv * 128 + li * 8);
        acc[0] += wa0 * bs2f(u.x); acc[1] += wa0 * bs2f(u.x >> 16);
        acc[2] += wa1 * bs2f(u.y); acc[3] += wa1 * bs2f(u.y >> 16);
        acc[4] += wa2 * bs2f(u.z); acc[5] += wa2 * bs2f(u.z >> 16);
        acc[6] += wa3 * bs2f(u.w); acc[7] += wa3 * bs2f(u.w >> 16);
      }
    }
  } else {
#pragma unroll 4
    for (int j = 0; j < deg; ++j) {
      int s = sS[wq][j];
      float4 wv = *(const float4*)(&sW[wq][j * 4]);
      uint4 u = *(const uint4*)(Wx + (size_t)s * 128 + li * 8);
      acc[0] += wv.x * bs2f(u.x); acc[1] += wv.x * bs2f(u.x >> 16);
      acc[2] += wv.y * bs2f(u.y); acc[3] += wv.y * bs2f(u.y >> 16);
      acc[4] += wv.z * bs2f(u.z); acc[5] += wv.z * bs2f(u.z >> 16);
      acc[6] += wv.w * bs2f(u.w); acc[7] += wv.w * bs2f(u.w >> 16);
    }
  }

  // fused scoring through the column permutation: true col = k*16+li, head=k>>1
  float invh[4];
  invh[0] = 1.0f / den4[0]; invh[1] = 1.0f / den4[1];
  invh[2] = 1.0f / den4[2]; invh[3] = 1.0f / den4[3];
  const float* mrow = msg + (size_t)b * 128;
  float dp = 0.f;
#pragma unroll
  for (int k = 0; k < 8; ++k) {
    int c = k * 16 + li;
    dp += (acc[k] * invh[k >> 1] + bias[c]) * mrow[c];
  }
#pragma unroll
  for (int o = 8; o >= 1; o >>= 1) dp += __shfl_xor(dp, o);
  if (li == 0) sdots[wq] = dp;
  __syncthreads();
  if (threadIdx.x < 16) {
    float d = sdots[threadIdx.x];
    float mx = d;
#pragma unroll
    for (int o = 1; o < 16; o <<= 1) mx = fmaxf(mx, __shfl_xor(mx, o));
    float ex = __expf(d - mx);
    float sum = ex;
#pragma unroll
    for (int o = 1; o < 16; o <<= 1) sum += __shfl_xor(sum, o);
    out[b * 16 + threadIdx.x] = d - mx - __logf(sum);
  }
}

extern "C" void kernel_launch(void* const* d_in, const int* in_sizes, int n_in,
                              void* d_out, int out_size, void* d_ws, size_t ws_size,
                              hipStream_t stream) {
  (void)in_sizes; (void)n_in; (void)out_size; (void)ws_size;
  const float* message = (const float*)d_in[0];
  const float* x       = (const float*)d_in[1];
  const int*   ei      = (const int*)d_in[2];
  const int*   indices = (const int*)d_in[3];
  const float* W       = (const float*)d_in[4];
  const float* att_src = (const float*)d_in[5];
  const float* att_dst = (const float*)d_in[6];
  const float* bias    = (const float*)d_in[7];
  const float* fc_w    = (const float*)d_in[8];
  const float* fc_b    = (const float*)d_in[9];
  float* out = (float*)d_out;

  char* p = (char*)d_ws;
  auto alloc = [&](size_t bytes) -> char* {
    char* r = p;
    p += (bytes + 255) & ~(size_t)255;
    return r;
  };
  unsigned short* Wx = (unsigned short*)alloc((size_t)N_NODES * 128 * 2);
  float* a_s = (float*)alloc((size_t)N_NODES * 4 * 4);
  float* a_d = (float*)alloc((size_t)N_NODES * 4 * 4);
  unsigned short* Wtp = (unsigned short*)alloc((size_t)WTROWS * STR * 2);
  int* nidx      = (int*)alloc((size_t)N_NODES * 4);
  int* cnt       = (int*)alloc((size_t)NSLOTS * 4);
  int* srclist   = (int*)alloc((size_t)NSLOTS * 64 * 4);
  float* msg     = (float*)alloc((size_t)BATCH * 128 * 4);
  int* ticket    = (int*)alloc(4);

  k_prep<<<128, 256, 0, stream>>>(W, att_src, att_dst, Wtp, indices, nidx, cnt, ticket);
  k_mega<<<PERSIST_BLOCKS, 256, 0, stream>>>(x, Wtp, Wx, a_s, a_d, ei, indices, nidx,
                                             cnt, srclist, message, fc_w, fc_b, msg,
                                             ticket);
  k_aggscore<<<BATCH, 256, 0, stream>>>(a_s, a_d, Wx, indices, nidx, cnt, srclist,
                                        ei, bias, msg, out);
}

// Round 8
// 183.000 us; speedup vs baseline: 1.0076x; 1.0076x over previous
//
#include <hip/hip_runtime.h>
#include <stdint.h>
#include <stddef.h>

#define N_NODES 100000
#define N_EDGES 1600000
#define F_IN 128
#define EMB 128
#define HEADS 4
#define D_HEAD 32
#define HIDDEN 256
#define BATCH 2048
#define CANDS 16
#define NSLOTS 32768  /* BATCH*CANDS slots, one per index (dups share canonical srclist) */
#define WTROWS 144    /* 128 W cols + 8 att-projection rows + 8 zero pad */
#define STR 136       /* padded row stride (shorts) */

/* mega-kernel roles, INTERLEAVED by blockIdx (period 10: 3 wx / 1 msg / 6 scat)
   -- best measured schedule (R6: 55-57us vs contiguous 62, persistent 59-62). */
#define WX_BLOCKS 782    /* ceil(N_NODES/128); 2 chunks of 64 rows per block */
#define MSG_BLOCKS 256   /* 8 batch rows per block */
#define EDGE_QUADS 400000
#define EDGE_BLOCKS 1563 /* ceil(EDGE_QUADS/256), 4 edges per thread */
#define MEGA_BLOCKS 2610 /* 261 groups x 10 */

typedef __attribute__((ext_vector_type(8))) short v8s;
typedef __attribute__((ext_vector_type(4))) float v4f;

__device__ __forceinline__ unsigned short f2bs(float f) {
  unsigned int u = __builtin_bit_cast(unsigned int, f);
  u = (u + 0x7fffu + ((u >> 16) & 1u)) >> 16;
  return (unsigned short)u;
}
__device__ __forceinline__ float bs2f(unsigned int s) {
  unsigned int u = (s & 0xffffu) << 16;
  return __builtin_bit_cast(float, u);
}

// ------- prep: padded Wt^T (+att-projection rows) + slot-map dedup (no memset) -
__global__ __launch_bounds__(256) void k_prep(const float* __restrict__ W,
                                              const float* __restrict__ att_src,
                                              const float* __restrict__ att_dst,
                                              unsigned short* __restrict__ Wtp,
                                              const int* __restrict__ idx,
                                              int* __restrict__ nidx,
                                              int* __restrict__ cnt) {
  int i = blockIdx.x * 256 + threadIdx.x;
  if (i < 128 * STR) {
    int r = i / STR, c = i - r * STR;
    Wtp[i] = (c < 128) ? f2bs(W[c * 128 + r]) : (unsigned short)0;
  } else if (i < WTROWS * STR) {
    int ii = i - 128 * STR;
    int r = ii / STR, c = ii - r * STR;  // r: 0..15
    unsigned short v = 0;
    if (c < 128 && r < 8) {
      const float* att = (r < 4) ? att_src : att_dst;
      int hh = r & 3;
      float s = 0.f;
#pragma unroll
      for (int d = 0; d < 32; ++d) s += W[c * 128 + hh * 32 + d] * att[hh * 32 + d];
      v = f2bs(s);
    }
    Wtp[i] = v;
  }
  if (i < NSLOTS) {
    cnt[i] = 0;           // zero-init scatter counters in-kernel (no memset)
    nidx[idx[i]] = i;     // plain store; any winner is canonical
  }
}

// ---- MEGA: wx (MFMA) + msg GEMM + edge scatter, role-INTERLEAVED blocks ------
__global__ __launch_bounds__(256) void k_mega(const float* __restrict__ x,
                                              const unsigned short* __restrict__ Wtp,
                                              unsigned short* __restrict__ Wx,
                                              float* __restrict__ a_s,
                                              float* __restrict__ a_d,
                                              const int* __restrict__ ei,
                                              const int* __restrict__ idx,
                                              const int* __restrict__ nidx,
                                              int* __restrict__ cnt,
                                              int* __restrict__ srclist,
                                              const float* __restrict__ message,
                                              const float* __restrict__ fc_w,
                                              const float* __restrict__ fc_b,
                                              float* __restrict__ msg) {
  __shared__ unsigned short smem[WTROWS * STR];  // 39168 B, role-unioned
  int tid = threadIdx.x;
  int sub = blockIdx.x % 10, grp = blockIdx.x / 10;

  if (sub < 3) {
    // ================= wx role: Wx = x @ W, permuted-native output ===========
    // Wx[row*128 + m*8 + nt] = C[row, nt*16+m]; consumer maps head = k>>1.
    int wxid = grp * 3 + sub;
    if (wxid >= WX_BLOCKS) return;
    unsigned short* wt = smem;
    {
      const uint4* s = (const uint4*)Wtp;
      uint4* d = (uint4*)wt;
#pragma unroll
      for (int it = 0; it < 10; ++it) {
        int i = it * 256 + tid;
        if (i < WTROWS * STR / 8) d[i] = s[i];
      }
    }
    __syncthreads();  // wt visible to all waves

    int w = tid >> 6, lane = tid & 63;
    int m = lane & 15, quad = lane >> 4;

    for (int chunk = 0; chunk < 2; ++chunk) {
      int rbase = wxid * 128 + chunk * 64;
      int gr = rbase + w * 16 + m;
      if (gr >= N_NODES) gr = N_NODES - 1;
      const float* xrow = x + (size_t)gr * 128;

      v8s afrag[4];
#pragma unroll
      for (int t = 0; t < 4; ++t) {
        const float4* gp = (const float4*)(xrow + t * 32 + quad * 8);
        float4 f0 = gp[0], f1 = gp[1];
        v8s a;
        a[0] = (short)f2bs(f0.x); a[1] = (short)f2bs(f0.y);
        a[2] = (short)f2bs(f0.z); a[3] = (short)f2bs(f0.w);
        a[4] = (short)f2bs(f1.x); a[5] = (short)f2bs(f1.y);
        a[6] = (short)f2bs(f1.z); a[7] = (short)f2bs(f1.w);
        afrag[t] = a;
      }

      v4f acc[9];
#pragma unroll
      for (int nt = 0; nt < 9; ++nt) {
        v4f a0 = {0.f, 0.f, 0.f, 0.f};
        const unsigned short* brow = wt + (size_t)(nt * 16 + m) * STR;
#pragma unroll
        for (int t = 0; t < 4; ++t) {
          v8s b = *(const v8s*)(brow + t * 32 + quad * 8);
          a0 = __builtin_amdgcn_mfma_f32_16x16x32_bf16(afrag[t], b, a0, 0, 0, 0);
        }
        acc[nt] = a0;
      }

#pragma unroll
      for (int r = 0; r < 4; ++r) {
        int orow = rbase + w * 16 + quad * 4 + r;
        if (orow < N_NODES) {
          if (m < 4) a_s[(size_t)orow * 4 + m] = acc[8][r];
          else if (m < 8) a_d[(size_t)orow * 4 + m - 4] = acc[8][r];
          v8s v;
#pragma unroll
          for (int nt = 0; nt < 8; ++nt) v[nt] = (short)f2bs(acc[nt][r]);
          *(v8s*)(&Wx[(size_t)orow * 128 + m * 8]) = v;
        }
      }
    }
  } else if (sub == 3) {
    // ================= msg role: msg = message @ fc_w.T + fc_b ===============
    int msgid = grp;
    if (msgid >= MSG_BLOCKS) return;
    float* Sm = (float*)smem;            // [8][256] = 8 KB
    float* red = ((float*)smem) + 2048;  // [8*128]  = 4 KB
    int b0 = msgid * 8;
    for (int i = tid; i < 8 * 256; i += 256)
      Sm[i] = message[(size_t)b0 * 256 + i];
    __syncthreads();
    int e = tid & 127, half = tid >> 7;
    float acc[8];
#pragma unroll
    for (int r = 0; r < 8; ++r) acc[r] = 0.f;
    const float* wrow = fc_w + (size_t)e * 256 + half * 128;
    for (int k = 0; k < 128; k += 4) {
      float4 w4 = *(const float4*)(wrow + k);
#pragma unroll
      for (int r = 0; r < 8; ++r) {
        float4 m4 = *(const float4*)(&Sm[r * 256 + half * 128 + k]);
        acc[r] += m4.x * w4.x + m4.y * w4.y + m4.z * w4.z + m4.w * w4.w;
      }
    }
    __syncthreads();
    if (half == 0) {
#pragma unroll
      for (int r = 0; r < 8; ++r) red[r * 128 + e] = acc[r];
    }
    __syncthreads();
    if (half == 1) {
#pragma unroll
      for (int r = 0; r < 8; ++r) red[r * 128 + e] += acc[r];
    }
    __syncthreads();
    for (int i = tid; i < 1024; i += 256)
      msg[(size_t)b0 * 128 + i] = red[i] + fc_b[i & 127];
  } else {
    // ============ scatter role: 4 edges/thread, batched-ILP chains ===========
    int scid = grp * 6 + (sub - 4);
    if (scid >= EDGE_BLOCKS) return;
    int e4 = scid * 256 + tid;
    if (e4 >= EDGE_QUADS) return;
    int base = e4 * 4;
    int4 d4 = *(const int4*)(ei + N_EDGES + base);  // dsts
    int4 s4 = *(const int4*)(ei + base);            // srcs
    int dst[4] = {d4.x, d4.y, d4.z, d4.w};
    int src[4] = {s4.x, s4.y, s4.z, s4.w};
    unsigned int ni[4];
#pragma unroll
    for (int j = 0; j < 4; ++j) ni[j] = (unsigned int)nidx[dst[j]];
    bool ok[4];
#pragma unroll
    for (int j = 0; j < 4; ++j) {
      unsigned int c = ni[j] < NSLOTS ? ni[j] : 0u;
      ok[j] = (ni[j] < NSLOTS) && (idx[c] == dst[j]);
    }
#pragma unroll
    for (int j = 0; j < 4; ++j) {
      if (ok[j]) {
        int pos = atomicAdd(&cnt[ni[j]], 1);
        if (pos < 64) srclist[ni[j] * 64 + pos] = src[j];
      }
    }
  }
}

// ---- aggregation + scoring: 512 thr/block, HALF-WAVE (32 lanes) per slot -----
// 2 neighbor rows processed per iteration (half serial depth, 2x MLP vs R6's
// quarter-wave). Partial accs from the two 16-lane groups merge inside the
// scoring dot via one shfl_xor(dp,16); bias term added by lower group only.
__global__ __launch_bounds__(512) void k_aggscore(const float* __restrict__ a_s,
                                                  const float* __restrict__ a_d,
                                                  const unsigned short* __restrict__ Wx,
                                                  const int* __restrict__ idx,
                                                  const int* __restrict__ nidx,
                                                  const int* __restrict__ cnt,
                                                  const int* __restrict__ srclist,
                                                  const int* __restrict__ ei,
                                                  const float* __restrict__ bias,
                                                  const float* __restrict__ msg,
                                                  float* __restrict__ out) {
  __shared__ int sS[16][64];        // 4 KB
  __shared__ float sW[16][64 * 4];  // 16 KB
  __shared__ float sdots[16];
  int tid = threadIdx.x;
  int wave = tid >> 6, lane = tid & 63;
  int li5 = lane & 31;              // lane within half-wave
  int hw = wave * 2 + (lane >> 5);  // half-wave id = slot 0..15
  int li = li5 & 15;                // col-chunk lane
  int rh = li5 >> 4;                // row-half: 0 = even rows, 1 = odd rows
  int b = blockIdx.x;               // batch row
  int wid = b * 16 + hw;            // slot = (batch b, cand hw)
  int dst = idx[wid];
  int ci = nidx[dst];               // canonical slot owning srclist/cnt
  int degRaw = cnt[ci];
  int deg = degRaw < 64 ? degRaw : 64;
  float4 ad4 = *(const float4*)(a_d + (size_t)dst * 4);
  float4 dsum = {0.f, 0.f, 0.f, 0.f};
  for (int t = li5; t < deg; t += 32) {
    int sv = srclist[ci * 64 + t];
    float4 as = *(const float4*)(a_s + (size_t)sv * 4);
    float e0 = as.x + ad4.x; e0 = e0 > 0.f ? e0 : 0.2f * e0;
    float e1 = as.y + ad4.y; e1 = e1 > 0.f ? e1 : 0.2f * e1;
    float e2 = as.z + ad4.z; e2 = e2 > 0.f ? e2 : 0.2f * e2;
    float e3 = as.w + ad4.w; e3 = e3 > 0.f ? e3 : 0.2f * e3;
    float4 w4;
    w4.x = __expf(e0); w4.y = __expf(e1);
    w4.z = __expf(e2); w4.w = __expf(e3);
    sS[hw][t] = sv;
    *(float4*)(&sW[hw][t * 4]) = w4;
    dsum.x += w4.x; dsum.y += w4.y; dsum.z += w4.z; dsum.w += w4.w;
  }
  // sS/sW half-wave-private: same-wave LDS ordering suffices
  asm volatile("s_waitcnt lgkmcnt(0)" ::: "memory");

#pragma unroll
  for (int o = 16; o >= 1; o >>= 1) {  // reduce across 32 lanes (stays in half)
    dsum.x += __shfl_xor(dsum.x, o);
    dsum.y += __shfl_xor(dsum.y, o);
    dsum.z += __shfl_xor(dsum.z, o);
    dsum.w += __shfl_xor(dsum.w, o);
  }

  // self-loop weights, all four heads (lane's 8 elems span heads k>>1 = 0..3)
  float4 as4 = *(const float4*)(a_s + (size_t)dst * 4);
  float s0 = as4.x + ad4.x; s0 = s0 > 0.f ? s0 : 0.2f * s0;
  float s1 = as4.y + ad4.y; s1 = s1 > 0.f ? s1 : 0.2f * s1;
  float s2 = as4.z + ad4.z; s2 = s2 > 0.f ? s2 : 0.2f * s2;
  float s3 = as4.w + ad4.w; s3 = s3 > 0.f ? s3 : 0.2f * s3;
  float wself[4];
  wself[0] = __expf(s0); wself[1] = __expf(s1);
  wself[2] = __expf(s2); wself[3] = __expf(s3);
  float den4[4];
  den4[0] = dsum.x + wself[0]; den4[1] = dsum.y + wself[1];
  den4[2] = dsum.z + wself[2]; den4[3] = dsum.w + wself[3];

  float acc[8];
  if (rh == 0) {  // self contribution counted once (lower row-half)
    uint4 u = *(const uint4*)(Wx + (size_t)dst * 128 + li * 8);
    acc[0] = wself[0] * bs2f(u.x); acc[1] = wself[0] * bs2f(u.x >> 16);
    acc[2] = wself[1] * bs2f(u.y); acc[3] = wself[1] * bs2f(u.y >> 16);
    acc[4] = wself[2] * bs2f(u.z); acc[5] = wself[2] * bs2f(u.z >> 16);
    acc[6] = wself[3] * bs2f(u.w); acc[7] = wself[3] * bs2f(u.w >> 16);
  } else {
#pragma unroll
    for (int k = 0; k < 8; ++k) acc[k] = 0.f;
  }

  if (degRaw > 64) {
    // correctness-only fallback (P ~ 1e-20): lower half rescans all edges
    if (rh == 0) {
      den4[0] = wself[0]; den4[1] = wself[1];
      den4[2] = wself[2]; den4[3] = wself[3];
      for (int e = 0; e < N_EDGES; ++e) {
        if (ei[N_EDGES + e] == dst) {
          int sv = ei[e];
          float4 as = *(const float4*)(a_s + (size_t)sv * 4);
          float e0 = as.x + ad4.x; e0 = e0 > 0.f ? e0 : 0.2f * e0;
          float e1 = as.y + ad4.y; e1 = e1 > 0.f ? e1 : 0.2f * e1;
          float e2 = as.z + ad4.z; e2 = e2 > 0.f ? e2 : 0.2f * e2;
          float e3 = as.w + ad4.w; e3 = e3 > 0.f ? e3 : 0.2f * e3;
          float wa0 = __expf(e0), wa1 = __expf(e1);
          float wa2 = __expf(e2), wa3 = __expf(e3);
          den4[0] += wa0; den4[1] += wa1; den4[2] += wa2; den4[3] += wa3;
          uint4 u = *(const uint4*)(Wx + (size_t)sv * 128 + li * 8);
          acc[0] += wa0 * bs2f(u.x); acc[1] += wa0 * bs2f(u.x >> 16);
          acc[2] += wa1 * bs2f(u.y); acc[3] += wa1 * bs2f(u.y >> 16);
          acc[4] += wa2 * bs2f(u.z); acc[5] += wa2 * bs2f(u.z >> 16);
          acc[6] += wa3 * bs2f(u.w); acc[7] += wa3 * bs2f(u.w >> 16);
        }
      }
    } else {
#pragma unroll
      for (int k = 0; k < 8; ++k) acc[k] = 0.f;  // upper half contributes 0
    }
  } else {
    // two rows per iteration: this lane handles rows jj+rh
    for (int jj = 0; jj + rh < deg; jj += 2) {
      int j = jj + rh;
      int s = sS[hw][j];
      float4 wv = *(const float4*)(&sW[hw][j * 4]);
      uint4 u = *(const uint4*)(Wx + (size_t)s * 128 + li * 8);
      acc[0] += wv.x * bs2f(u.x); acc[1] += wv.x * bs2f(u.x >> 16);
      acc[2] += wv.y * bs2f(u.y); acc[3] += wv.y * bs2f(u.y >> 16);
      acc[4] += wv.z * bs2f(u.z); acc[5] += wv.z * bs2f(u.z >> 16);
      acc[6] += wv.w * bs2f(u.w); acc[7] += wv.w * bs2f(u.w >> 16);
    }
  }

  // scoring through the column permutation: true col = k*16+li, head = k>>1
  float invh[4];
  invh[0] = 1.0f / den4[0]; invh[1] = 1.0f / den4[1];
  invh[2] = 1.0f / den4[2]; invh[3] = 1.0f / den4[3];
  const float* mrow = msg + (size_t)b * 128;
  float dp = 0.f;
#pragma unroll
  for (int k = 0; k < 8; ++k) {
    int c = k * 16 + li;
    float v = acc[k] * invh[k >> 1];
    if (rh == 0) v += bias[c];  // bias counted once
    dp += v * mrow[c];
  }
#pragma unroll
  for (int o = 16; o >= 1; o >>= 1) dp += __shfl_xor(dp, o);  // 32-lane reduce
  if (li5 == 0) sdots[hw] = dp;
  __syncthreads();
  if (tid < 16) {
    float d = sdots[tid];
    float mx = d;
#pragma unroll
    for (int o = 1; o < 16; o <<= 1) mx = fmaxf(mx, __shfl_xor(mx, o));
    float ex = __expf(d - mx);
    float sum = ex;
#pragma unroll
    for (int o = 1; o < 16; o <<= 1) sum += __shfl_xor(sum, o);
    out[b * 16 + tid] = d - mx - __logf(sum);
  }
}

extern "C" void kernel_launch(void* const* d_in, const int* in_sizes, int n_in,
                              void* d_out, int out_size, void* d_ws, size_t ws_size,
                              hipStream_t stream) {
  (void)in_sizes; (void)n_in; (void)out_size; (void)ws_size;
  const float* message = (const float*)d_in[0];
  const float* x       = (const float*)d_in[1];
  const int*   ei      = (const int*)d_in[2];
  const int*   indices = (const int*)d_in[3];
  const float* W       = (const float*)d_in[4];
  const float* att_src = (const float*)d_in[5];
  const float* att_dst = (const float*)d_in[6];
  const float* bias    = (const float*)d_in[7];
  const float* fc_w    = (const float*)d_in[8];
  const float* fc_b    = (const float*)d_in[9];
  float* out = (float*)d_out;

  char* p = (char*)d_ws;
  auto alloc = [&](size_t bytes) -> char* {
    char* r = p;
    p += (bytes + 255) & ~(size_t)255;
    return r;
  };
  unsigned short* Wx = (unsigned short*)alloc((size_t)N_NODES * 128 * 2);
  float* a_s = (float*)alloc((size_t)N_NODES * 4 * 4);
  float* a_d = (float*)alloc((size_t)N_NODES * 4 * 4);
  unsigned short* Wtp = (unsigned short*)alloc((size_t)WTROWS * STR * 2);
  int* nidx      = (int*)alloc((size_t)N_NODES * 4);
  int* cnt       = (int*)alloc((size_t)NSLOTS * 4);
  int* srclist   = (int*)alloc((size_t)NSLOTS * 64 * 4);
  float* msg     = (float*)alloc((size_t)BATCH * 128 * 4);

  k_prep<<<128, 256, 0, stream>>>(W, att_src, att_dst, Wtp, indices, nidx, cnt);
  k_mega<<<MEGA_BLOCKS, 256, 0, stream>>>(x, Wtp, Wx, a_s, a_d, ei, indices, nidx,
                                          cnt, srclist, message, fc_w, fc_b, msg);
  k_aggscore<<<BATCH, 512, 0, stream>>>(a_s, a_d, Wx, indices, nidx, cnt, srclist,
                                        ei, bias, msg, out);
}

// Round 9
// 175.100 us; speedup vs baseline: 1.0531x; 1.0451x over previous
//
#include <hip/hip_runtime.h>
#include <stdint.h>
#include <stddef.h>

#define N_NODES 100000
#define N_EDGES 1600000
#define F_IN 128
#define EMB 128
#define HEADS 4
#define D_HEAD 32
#define HIDDEN 256
#define BATCH 2048
#define CANDS 16
#define NSLOTS 32768  /* BATCH*CANDS slots, one per index (dups share canonical srclist) */
#define WTROWS 144    /* 128 W cols + 8 att-projection rows + 8 zero pad */
#define STR 136       /* padded row stride (shorts) */

/* mega-kernel roles, INTERLEAVED by blockIdx (period 7: 3 wx / 1 msg / 3 scat).
   Scatter at 8 edges/thread (2x R6's MLP) -> 782 scatter blocks, grid 1827. */
#define WX_BLOCKS 782    /* ceil(N_NODES/128); 2 chunks of 64 rows per block */
#define MSG_BLOCKS 256   /* 8 batch rows per block */
#define EDGE_OCTS 200000 /* N_EDGES/8 */
#define EDGE_BLOCKS 782  /* ceil(EDGE_OCTS/256), 8 edges per thread */
#define MEGA_BLOCKS 1827 /* 261 groups x 7 */

typedef __attribute__((ext_vector_type(8))) short v8s;
typedef __attribute__((ext_vector_type(4))) float v4f;

__device__ __forceinline__ unsigned short f2bs(float f) {
  unsigned int u = __builtin_bit_cast(unsigned int, f);
  u = (u + 0x7fffu + ((u >> 16) & 1u)) >> 16;
  return (unsigned short)u;
}
__device__ __forceinline__ float bs2f(unsigned int s) {
  unsigned int u = (s & 0xffffu) << 16;
  return __builtin_bit_cast(float, u);
}

// ------- prep: padded Wt^T (+att-projection rows) + slot-map dedup (no memset) -
__global__ __launch_bounds__(256) void k_prep(const float* __restrict__ W,
                                              const float* __restrict__ att_src,
                                              const float* __restrict__ att_dst,
                                              unsigned short* __restrict__ Wtp,
                                              const int* __restrict__ idx,
                                              int* __restrict__ nidx,
                                              int* __restrict__ cnt) {
  int i = blockIdx.x * 256 + threadIdx.x;
  if (i < 128 * STR) {
    int r = i / STR, c = i - r * STR;
    Wtp[i] = (c < 128) ? f2bs(W[c * 128 + r]) : (unsigned short)0;
  } else if (i < WTROWS * STR) {
    int ii = i - 128 * STR;
    int r = ii / STR, c = ii - r * STR;  // r: 0..15
    unsigned short v = 0;
    if (c < 128 && r < 8) {
      const float* att = (r < 4) ? att_src : att_dst;
      int hh = r & 3;
      float s = 0.f;
#pragma unroll
      for (int d = 0; d < 32; ++d) s += W[c * 128 + hh * 32 + d] * att[hh * 32 + d];
      v = f2bs(s);
    }
    Wtp[i] = v;
  }
  if (i < NSLOTS) {
    cnt[i] = 0;           // zero-init scatter counters in-kernel (no memset)
    nidx[idx[i]] = i;     // plain store; any winner is canonical
  }
}

// ---- MEGA: wx (MFMA) + msg GEMM + edge scatter, role-INTERLEAVED blocks ------
__global__ __launch_bounds__(256) void k_mega(const float* __restrict__ x,
                                              const unsigned short* __restrict__ Wtp,
                                              unsigned short* __restrict__ Wx,
                                              float* __restrict__ a_s,
                                              float* __restrict__ a_d,
                                              const int* __restrict__ ei,
                                              const int* __restrict__ idx,
                                              const int* __restrict__ nidx,
                                              int* __restrict__ cnt,
                                              int* __restrict__ srclist,
                                              const float* __restrict__ message,
                                              const float* __restrict__ fc_w,
                                              const float* __restrict__ fc_b,
                                              float* __restrict__ msg) {
  __shared__ unsigned short smem[WTROWS * STR];  // 39168 B, role-unioned
  int tid = threadIdx.x;
  int sub = blockIdx.x % 7, grp = blockIdx.x / 7;

  if (sub < 3) {
    // ================= wx role: Wx = x @ W, permuted-native output ===========
    // Wx[row*128 + m*8 + nt] = C[row, nt*16+m]; consumer maps head = k>>1.
    int wxid = grp * 3 + sub;
    if (wxid >= WX_BLOCKS) return;
    unsigned short* wt = smem;
    {
      const uint4* s = (const uint4*)Wtp;
      uint4* d = (uint4*)wt;
#pragma unroll
      for (int it = 0; it < 10; ++it) {
        int i = it * 256 + tid;
        if (i < WTROWS * STR / 8) d[i] = s[i];
      }
    }
    __syncthreads();  // wt visible to all waves

    int w = tid >> 6, lane = tid & 63;
    int m = lane & 15, quad = lane >> 4;

    for (int chunk = 0; chunk < 2; ++chunk) {
      int rbase = wxid * 128 + chunk * 64;
      int gr = rbase + w * 16 + m;
      if (gr >= N_NODES) gr = N_NODES - 1;
      const float* xrow = x + (size_t)gr * 128;

      v8s afrag[4];
#pragma unroll
      for (int t = 0; t < 4; ++t) {
        const float4* gp = (const float4*)(xrow + t * 32 + quad * 8);
        float4 f0 = gp[0], f1 = gp[1];
        v8s a;
        a[0] = (short)f2bs(f0.x); a[1] = (short)f2bs(f0.y);
        a[2] = (short)f2bs(f0.z); a[3] = (short)f2bs(f0.w);
        a[4] = (short)f2bs(f1.x); a[5] = (short)f2bs(f1.y);
        a[6] = (short)f2bs(f1.z); a[7] = (short)f2bs(f1.w);
        afrag[t] = a;
      }

      v4f acc[9];
#pragma unroll
      for (int nt = 0; nt < 9; ++nt) {
        v4f a0 = {0.f, 0.f, 0.f, 0.f};
        const unsigned short* brow = wt + (size_t)(nt * 16 + m) * STR;
#pragma unroll
        for (int t = 0; t < 4; ++t) {
          v8s b = *(const v8s*)(brow + t * 32 + quad * 8);
          a0 = __builtin_amdgcn_mfma_f32_16x16x32_bf16(afrag[t], b, a0, 0, 0, 0);
        }
        acc[nt] = a0;
      }

#pragma unroll
      for (int r = 0; r < 4; ++r) {
        int orow = rbase + w * 16 + quad * 4 + r;
        if (orow < N_NODES) {
          if (m < 4) a_s[(size_t)orow * 4 + m] = acc[8][r];
          else if (m < 8) a_d[(size_t)orow * 4 + m - 4] = acc[8][r];
          v8s v;
#pragma unroll
          for (int nt = 0; nt < 8; ++nt) v[nt] = (short)f2bs(acc[nt][r]);
          *(v8s*)(&Wx[(size_t)orow * 128 + m * 8]) = v;
        }
      }
    }
  } else if (sub == 3) {
    // ================= msg role: msg = message @ fc_w.T + fc_b ===============
    int msgid = grp;
    if (msgid >= MSG_BLOCKS) return;
    float* Sm = (float*)smem;            // [8][256] = 8 KB
    float* red = ((float*)smem) + 2048;  // [8*128]  = 4 KB
    int b0 = msgid * 8;
    for (int i = tid; i < 8 * 256; i += 256)
      Sm[i] = message[(size_t)b0 * 256 + i];
    __syncthreads();
    int e = tid & 127, half = tid >> 7;
    float acc[8];
#pragma unroll
    for (int r = 0; r < 8; ++r) acc[r] = 0.f;
    const float* wrow = fc_w + (size_t)e * 256 + half * 128;
    for (int k = 0; k < 128; k += 4) {
      float4 w4 = *(const float4*)(wrow + k);
#pragma unroll
      for (int r = 0; r < 8; ++r) {
        float4 m4 = *(const float4*)(&Sm[r * 256 + half * 128 + k]);
        acc[r] += m4.x * w4.x + m4.y * w4.y + m4.z * w4.z + m4.w * w4.w;
      }
    }
    __syncthreads();
    if (half == 0) {
#pragma unroll
      for (int r = 0; r < 8; ++r) red[r * 128 + e] = acc[r];
    }
    __syncthreads();
    if (half == 1) {
#pragma unroll
      for (int r = 0; r < 8; ++r) red[r * 128 + e] += acc[r];
    }
    __syncthreads();
    for (int i = tid; i < 1024; i += 256)
      msg[(size_t)b0 * 128 + i] = red[i] + fc_b[i & 127];
  } else {
    // ======== scatter role: 8 edges/thread, 8 independent gather chains ======
    int scid = grp * 3 + (sub - 4);
    if (scid >= EDGE_BLOCKS) return;
    int e8 = scid * 256 + tid;
    if (e8 >= EDGE_OCTS) return;
    int base = e8 * 8;
    int4 da = *(const int4*)(ei + N_EDGES + base);      // dsts 0..3
    int4 db = *(const int4*)(ei + N_EDGES + base + 4);  // dsts 4..7
    int4 sa = *(const int4*)(ei + base);                // srcs 0..3
    int4 sb = *(const int4*)(ei + base + 4);            // srcs 4..7
    int dst[8] = {da.x, da.y, da.z, da.w, db.x, db.y, db.z, db.w};
    int src[8] = {sa.x, sa.y, sa.z, sa.w, sb.x, sb.y, sb.z, sb.w};
    unsigned int ni[8];
#pragma unroll
    for (int j = 0; j < 8; ++j) ni[j] = (unsigned int)nidx[dst[j]];  // 8 indep
    bool ok[8];
#pragma unroll
    for (int j = 0; j < 8; ++j) {
      unsigned int c = ni[j] < NSLOTS ? ni[j] : 0u;  // clamp for spec. load
      ok[j] = (ni[j] < NSLOTS) && (idx[c] == dst[j]);  // 8 indep validates
    }
#pragma unroll
    for (int j = 0; j < 8; ++j) {
      if (ok[j]) {
        int pos = atomicAdd(&cnt[ni[j]], 1);
        if (pos < 64) srclist[ni[j] * 64 + pos] = src[j];
      }
    }
  }
}

// ---- per-slot aggregation + fused scoring: block b = 16 cands of batch row b --
// (R6 version verbatim: 256 thr, quarter-wave per slot.)
// Wx is column-permuted (see wx role); lane li's k-th value is true col k*16+li,
// head = k>>1. All attention weights kept per-head (float4), selected by k>>1.
__global__ __launch_bounds__(256) void k_aggscore(const float* __restrict__ a_s,
                                                  const float* __restrict__ a_d,
                                                  const unsigned short* __restrict__ Wx,
                                                  const int* __restrict__ idx,
                                                  const int* __restrict__ nidx,
                                                  const int* __restrict__ cnt,
                                                  const int* __restrict__ srclist,
                                                  const int* __restrict__ ei,
                                                  const float* __restrict__ bias,
                                                  const float* __restrict__ msg,
                                                  float* __restrict__ out) {
  __shared__ int sS[16][64];
  __shared__ float sW[16][64 * 4];
  __shared__ float sdots[16];
  int w = threadIdx.x >> 6, lane = threadIdx.x & 63;
  int q = lane >> 4, li = lane & 15;
  int wq = w * 4 + q;
  int b = blockIdx.x;            // batch row
  int wid = b * 16 + wq;         // slot = (batch b, cand wq)
  int dst = idx[wid];
  int ci = nidx[dst];            // canonical slot owning srclist/cnt for dst
  int degRaw = cnt[ci];
  int deg = degRaw < 64 ? degRaw : 64;
  float4 ad4 = *(const float4*)(a_d + (size_t)dst * 4);
  float4 dsum = {0.f, 0.f, 0.f, 0.f};
  for (int t = li; t < deg; t += 16) {
    int sv = srclist[ci * 64 + t];
    float4 as = *(const float4*)(a_s + (size_t)sv * 4);
    float e0 = as.x + ad4.x; e0 = e0 > 0.f ? e0 : 0.2f * e0;
    float e1 = as.y + ad4.y; e1 = e1 > 0.f ? e1 : 0.2f * e1;
    float e2 = as.z + ad4.z; e2 = e2 > 0.f ? e2 : 0.2f * e2;
    float e3 = as.w + ad4.w; e3 = e3 > 0.f ? e3 : 0.2f * e3;
    float4 w4;
    w4.x = __expf(e0); w4.y = __expf(e1);
    w4.z = __expf(e2); w4.w = __expf(e3);
    sS[wq][t] = sv;
    *(float4*)(&sW[wq][t * 4]) = w4;
    dsum.x += w4.x; dsum.y += w4.y; dsum.z += w4.z; dsum.w += w4.w;
  }
  // sS/sW are quarter-wave-private: same-wave LDS ordering suffices
  asm volatile("s_waitcnt lgkmcnt(0)" ::: "memory");

#pragma unroll
  for (int o = 8; o >= 1; o >>= 1) {
    dsum.x += __shfl_xor(dsum.x, o);
    dsum.y += __shfl_xor(dsum.y, o);
    dsum.z += __shfl_xor(dsum.z, o);
    dsum.w += __shfl_xor(dsum.w, o);
  }

  // self-loop weights, ALL four heads (lane's 8 elems span heads k>>1=0..3)
  float4 as4 = *(const float4*)(a_s + (size_t)dst * 4);
  float s0 = as4.x + ad4.x; s0 = s0 > 0.f ? s0 : 0.2f * s0;
  float s1 = as4.y + ad4.y; s1 = s1 > 0.f ? s1 : 0.2f * s1;
  float s2 = as4.z + ad4.z; s2 = s2 > 0.f ? s2 : 0.2f * s2;
  float s3 = as4.w + ad4.w; s3 = s3 > 0.f ? s3 : 0.2f * s3;
  float wself[4];
  wself[0] = __expf(s0); wself[1] = __expf(s1);
  wself[2] = __expf(s2); wself[3] = __expf(s3);
  float den4[4];
  den4[0] = dsum.x + wself[0]; den4[1] = dsum.y + wself[1];
  den4[2] = dsum.z + wself[2]; den4[3] = dsum.w + wself[3];

  float acc[8];
  {
    uint4 u = *(const uint4*)(Wx + (size_t)dst * 128 + li * 8);
    acc[0] = wself[0] * bs2f(u.x); acc[1] = wself[0] * bs2f(u.x >> 16);
    acc[2] = wself[1] * bs2f(u.y); acc[3] = wself[1] * bs2f(u.y >> 16);
    acc[4] = wself[2] * bs2f(u.z); acc[5] = wself[2] * bs2f(u.z >> 16);
    acc[6] = wself[3] * bs2f(u.w); acc[7] = wself[3] * bs2f(u.w >> 16);
  }

  if (degRaw > 64) {
    // correctness-only fallback (P ~ 1e-20): serial full-edge rescan
    den4[0] = wself[0]; den4[1] = wself[1];
    den4[2] = wself[2]; den4[3] = wself[3];
    for (int e = 0; e < N_EDGES; ++e) {
      if (ei[N_EDGES + e] == dst) {
        int sv = ei[e];
        float4 as = *(const float4*)(a_s + (size_t)sv * 4);
        float e0 = as.x + ad4.x; e0 = e0 > 0.f ? e0 : 0.2f * e0;
        float e1 = as.y + ad4.y; e1 = e1 > 0.f ? e1 : 0.2f * e1;
        float e2 = as.z + ad4.z; e2 = e2 > 0.f ? e2 : 0.2f * e2;
        float e3 = as.w + ad4.w; e3 = e3 > 0.f ? e3 : 0.2f * e3;
        float wa0 = __expf(e0), wa1 = __expf(e1);
        float wa2 = __expf(e2), wa3 = __expf(e3);
        den4[0] += wa0; den4[1] += wa1; den4[2] += wa2; den4[3] += wa3;
        uint4 u = *(const uint4*)(Wx + (size_t)sv * 128 + li * 8);
        acc[0] += wa0 * bs2f(u.x); acc[1] += wa0 * bs2f(u.x >> 16);
        acc[2] += wa1 * bs2f(u.y); acc[3] += wa1 * bs2f(u.y >> 16);
        acc[4] += wa2 * bs2f(u.z); acc[5] += wa2 * bs2f(u.z >> 16);
        acc[6] += wa3 * bs2f(u.w); acc[7] += wa3 * bs2f(u.w >> 16);
      }
    }
  } else {
#pragma unroll 4
    for (int j = 0; j < deg; ++j) {
      int s = sS[wq][j];
      float4 wv = *(const float4*)(&sW[wq][j * 4]);
      uint4 u = *(const uint4*)(Wx + (size_t)s * 128 + li * 8);
      acc[0] += wv.x * bs2f(u.x); acc[1] += wv.x * bs2f(u.x >> 16);
      acc[2] += wv.y * bs2f(u.y); acc[3] += wv.y * bs2f(u.y >> 16);
      acc[4] += wv.z * bs2f(u.z); acc[5] += wv.z * bs2f(u.z >> 16);
      acc[6] += wv.w * bs2f(u.w); acc[7] += wv.w * bs2f(u.w >> 16);
    }
  }

  // fused scoring through the column permutation: true col = k*16+li, head=k>>1
  float invh[4];
  invh[0] = 1.0f / den4[0]; invh[1] = 1.0f / den4[1];
  invh[2] = 1.0f / den4[2]; invh[3] = 1.0f / den4[3];
  const float* mrow = msg + (size_t)b * 128;
  float dp = 0.f;
#pragma unroll
  for (int k = 0; k < 8; ++k) {
    int c = k * 16 + li;
    dp += (acc[k] * invh[k >> 1] + bias[c]) * mrow[c];
  }
#pragma unroll
  for (int o = 8; o >= 1; o >>= 1) dp += __shfl_xor(dp, o);
  if (li == 0) sdots[wq] = dp;
  __syncthreads();
  if (threadIdx.x < 16) {
    float d = sdots[threadIdx.x];
    float mx = d;
#pragma unroll
    for (int o = 1; o < 16; o <<= 1) mx = fmaxf(mx, __shfl_xor(mx, o));
    float ex = __expf(d - mx);
    float sum = ex;
#pragma unroll
    for (int o = 1; o < 16; o <<= 1) sum += __shfl_xor(sum, o);
    out[b * 16 + threadIdx.x] = d - mx - __logf(sum);
  }
}

extern "C" void kernel_launch(void* const* d_in, const int* in_sizes, int n_in,
                              void* d_out, int out_size, void* d_ws, size_t ws_size,
                              hipStream_t stream) {
  (void)in_sizes; (void)n_in; (void)out_size; (void)ws_size;
  const float* message = (const float*)d_in[0];
  const float* x       = (const float*)d_in[1];
  const int*   ei      = (const int*)d_in[2];
  const int*   indices = (const int*)d_in[3];
  const float* W       = (const float*)d_in[4];
  const float* att_src = (const float*)d_in[5];
  const float* att_dst = (const float*)d_in[6];
  const float* bias    = (const float*)d_in[7];
  const float* fc_w    = (const float*)d_in[8];
  const float* fc_b    = (const float*)d_in[9];
  float* out = (float*)d_out;

  char* p = (char*)d_ws;
  auto alloc = [&](size_t bytes) -> char* {
    char* r = p;
    p += (bytes + 255) & ~(size_t)255;
    return r;
  };
  unsigned short* Wx = (unsigned short*)alloc((size_t)N_NODES * 128 * 2);
  float* a_s = (float*)alloc((size_t)N_NODES * 4 * 4);
  float* a_d = (float*)alloc((size_t)N_NODES * 4 * 4);
  unsigned short* Wtp = (unsigned short*)alloc((size_t)WTROWS * STR * 2);
  int* nidx      = (int*)alloc((size_t)N_NODES * 4);
  int* cnt       = (int*)alloc((size_t)NSLOTS * 4);
  int* srclist   = (int*)alloc((size_t)NSLOTS * 64 * 4);
  float* msg     = (float*)alloc((size_t)BATCH * 128 * 4);

  k_prep<<<128, 256, 0, stream>>>(W, att_src, att_dst, Wtp, indices, nidx, cnt);
  k_mega<<<MEGA_BLOCKS, 256, 0, stream>>>(x, Wtp, Wx, a_s, a_d, ei, indices, nidx,
                                          cnt, srclist, message, fc_w, fc_b, msg);
  k_aggscore<<<BATCH, 256, 0, stream>>>(a_s, a_d, Wx, indices, nidx, cnt, srclist,
                                        ei, bias, msg, out);
}